// Round 7
// baseline (23.825 us; speedup 1.0000x reference)
//
#include <hip/hip_runtime.h>

// Wiener-Hammerstein, exact chunk-state passing, MANY SMALL STAGGERED BLOCKS.
//   y1 = IIR(b1,a1,n_k=1)(u);  v = whf(y1);  out = IIR(b2,a2,n_k=0)(v)
// R6 post-mortem: monolithic one-row blocks serialize load/compute/store
// phases chip-wide (21.3us vs ~11us floor, invariant to occupancy). This
// version: 4608 single-wave blocks (512 rows x 9 segments); each 64-lane
// block owns 59 output chunks (CH=32) + 5 halo lanes. State dependency is
// only 3 chunks deep (truncated scan: E1 = D1[c-1]+A1*D1[c-2], trunc
// rho1^64~7e-9; E2 = D2[c-1]+A2*D2[c-2]+A2^2*D2[c-3], trunc rho2^96~3.5e-5),
// so halo lanes make blocks self-contained; tails move by __shfl_up (no
// barriers). u staged f32 in LDS (K=65 odd stride = conflict-free both
// ways); out staged through the SAME buffer (aliased) for coalesced stores.

constexpr int T_LEN = 16384;
constexpr int CH    = 32;          // samples per chunk (= per thread)
constexpr int HALO  = 5;           // halo lanes per block
constexpr int OUTCH = 64 - HALO;   // 59 output chunks per block
constexpr int SEGS  = 9;           // ceil(512 / 59)
constexpr int KS    = 65;          // staged chunks: base-6 .. base+58

__global__ __launch_bounds__(64, 4)
void whsys_kernel(const float* __restrict__ u,
                  const float* __restrict__ b1v, const float* __restrict__ a1v,
                  const float* __restrict__ b2v, const float* __restrict__ a2v,
                  float* __restrict__ out)
{
    __shared__ float4 sq[8 * KS];   // 8320 B: u quads [m][k]; later out staging

    const int l    = threadIdx.x;
    const int seg  = blockIdx.x;
    const int base = seg * OUTCH;   // first output chunk of this block
    const float* __restrict__ urow = u   + (size_t)blockIdx.y * T_LEN;
    float*       __restrict__ orow = out + (size_t)blockIdx.y * T_LEN;

    const float a10=a1v[0], a11=a1v[1], a12=a1v[2];
    const float b10=b1v[0], b11=b1v[1], b12=b1v[2];
    const float a20=a2v[0], a21=a2v[1], a22=a2v[2];
    const float b20=b2v[0], b21=b2v[1], b22=b2v[2];

    // ---- stage u: chunks base-6 .. base+58 (2080 samples, f32) -------------
    // quad f4 holds samples 4*f4..4*f4+3 -> slot [f4&7][f4>>3]; KS=65 odd
    // stride => consecutive f4 hit distinct float4-banks (write) and
    // consecutive k at fixed m (read) likewise. Zero-fill outside [0,T).
    const int t00 = (base - 6) * CH;
    #pragma unroll
    for (int it = 0; it < 9; ++it) {
        const int f4 = it * 64 + l;
        if (f4 < 520) {
            const int t = t00 + 4 * f4;
            float4 v = make_float4(0.f, 0.f, 0.f, 0.f);
            if (t >= 0 && t < T_LEN)
                v = *reinterpret_cast<const float4*>(urow + t);
            sq[(f4 & 7) * KS + (f4 >> 3)] = v;
        }
    }

    // ---- A1 = C1^32; A2 = C2^32; A2q = C2^64 (overlaps the loads) ----------
    float A1[9] = {-a10,-a11,-a12, 1.f,0.f,0.f, 0.f,1.f,0.f};
    float A2[9] = {-a20,-a21,-a22, 1.f,0.f,0.f, 0.f,1.f,0.f};
    float A2q[9];
    #pragma unroll
    for (int itq = 0; itq < 5; ++itq) {
        float B1[9], B2[9];
        #pragma unroll
        for (int i = 0; i < 3; ++i)
            #pragma unroll
            for (int j = 0; j < 3; ++j) {
                B1[i*3+j] = fmaf(A1[i*3], A1[j], fmaf(A1[i*3+1], A1[3+j], A1[i*3+2]*A1[6+j]));
                B2[i*3+j] = fmaf(A2[i*3], A2[j], fmaf(A2[i*3+1], A2[3+j], A2[i*3+2]*A2[6+j]));
            }
        #pragma unroll
        for (int i = 0; i < 9; ++i) { A1[i] = B1[i]; A2[i] = B2[i]; }
    }
    #pragma unroll
    for (int i = 0; i < 3; ++i)
        #pragma unroll
        for (int j = 0; j < 3; ++j)
            A2q[i*3+j] = fmaf(A2[i*3], A2[j], fmaf(A2[i*3+1], A2[3+j], A2[i*3+2]*A2[6+j]));

    __syncthreads();   // single wave: cheap (waitcnt + s_barrier)

    auto whf = [](float y) -> float {   // -elu(-10/11 y) = med3(ky, 1-e^-ky, 0)
        const float t1 = 0.9090909090909091f * y;
        const float e  = 1.f - __expf(-t1);
        return __builtin_amdgcn_fmed3f(t1, e, 0.f);
    };

    // ---- pass 1: stage-1 local (zero y-init, true u), chunk base+l-5 -------
    float arr[32];
    float yr1, yr2, yr3;
    {
        const float4 up = sq[7 * KS + l];        // tail quad of chunk (own-1)
        float u1 = up.w, u2 = up.z, u3 = up.y;   // u[-1], u[-2], u[-3]
        float y1 = 0.f, y2 = 0.f, y3 = 0.f;
        #pragma unroll
        for (int m = 0; m < 8; ++m) {
            const float4 uu = sq[m * KS + (l + 1)];
            const float us[4] = {uu.x, uu.y, uu.z, uu.w};
            #pragma unroll
            for (int e = 0; e < 4; ++e) {
                const float x = fmaf(b12,u3, fmaf(b11,u2, b10*u1));
                const float y = fmaf(-a10,y1, fmaf(-a11,y2, fmaf(-a12,y3, x)));
                arr[m*4+e] = y;
                u3=u2; u2=u1; u1=us[e];
                y3=y2; y2=y1; y1=y;
            }
        }
        yr1=y1; yr2=y2; yr3=y3;                  // D1 = (y[31], y[30], y[29])
    }

    // ---- D1 tails via shuffles; E1 = D1[c-1] + A1*D1[c-2] ------------------
    float p1 = __shfl_up(yr1,1), p2 = __shfl_up(yr2,1), p3 = __shfl_up(yr3,1);
    float q1 = __shfl_up(yr1,2), q2 = __shfl_up(yr2,2), q3 = __shfl_up(yr3,2);
    if (l < 1) { p1=0.f; p2=0.f; p3=0.f; }
    if (l < 2) { q1=0.f; q2=0.f; q3=0.f; }
    float h1 = fmaf(A1[0],q1, fmaf(A1[1],q2, fmaf(A1[2],q3, p1)));
    float h2 = fmaf(A1[3],q1, fmaf(A1[4],q2, fmaf(A1[5],q3, p2)));
    float h3 = fmaf(A1[6],q1, fmaf(A1[7],q2, fmaf(A1[8],q3, p3)));
    float v_m1 = whf(p1), v_m2 = whf(p2);        // v[-1], v[-2] (local tails)

    // ---- pass 2: correct y1 + whf + stage-2 local (fused) ------------------
    float z1 = 0.f, z2 = 0.f, z3 = 0.f;
    #pragma unroll
    for (int j = 0; j < 32; ++j) {
        const float hn = fmaf(-a10,h1, fmaf(-a11,h2, -a12*h3));
        h3=h2; h2=h1; h1=hn;
        const float v = whf(arr[j] + hn);
        const float x = fmaf(b22,v_m2, fmaf(b21,v_m1, b20*v));
        const float z = fmaf(-a20,z1, fmaf(-a21,z2, fmaf(-a22,z3, x)));
        v_m2=v_m1; v_m1=v;
        z3=z2; z2=z1; z1=z;
        arr[j] = z;                              // y2 local
    }

    // ---- D2 tails; E2 = D2[c-1] + A2*D2[c-2] + A2q*D2[c-3] -----------------
    float r1=__shfl_up(z1,1), r2=__shfl_up(z2,1), r3=__shfl_up(z3,1);
    float s1=__shfl_up(z1,2), s2=__shfl_up(z2,2), s3=__shfl_up(z3,2);
    float t1=__shfl_up(z1,3), t2=__shfl_up(z2,3), t3=__shfl_up(z3,3);
    if (l < 1) { r1=0.f; r2=0.f; r3=0.f; }
    if (l < 2) { s1=0.f; s2=0.f; s3=0.f; }
    if (l < 3) { t1=0.f; t2=0.f; t3=0.f; }
    float g1 = fmaf(A2[0],s1, fmaf(A2[1],s2, fmaf(A2[2],s3,
               fmaf(A2q[0],t1, fmaf(A2q[1],t2, fmaf(A2q[2],t3, r1))))));
    float g2 = fmaf(A2[3],s1, fmaf(A2[4],s2, fmaf(A2[5],s3,
               fmaf(A2q[3],t1, fmaf(A2q[4],t2, fmaf(A2q[5],t3, r2))))));
    float g3 = fmaf(A2[6],s1, fmaf(A2[7],s2, fmaf(A2[8],s3,
               fmaf(A2q[6],t1, fmaf(A2q[7],t2, fmaf(A2q[8],t3, r3))))));
    #pragma unroll
    for (int j = 0; j < 32; ++j) {
        const float gn = fmaf(-a20,g1, fmaf(-a21,g2, -a22*g3));
        g3=g2; g2=g1; g1=gn;
        arr[j] += gn;
    }
    __syncthreads();

    // ---- out staging (aliases sq) + coalesced masked store ------------------
    float4* o_st = sq;                           // 512 float4 <= 520
    #pragma unroll
    for (int q8 = 0; q8 < 8; ++q8)
        o_st[l * 8 + (q8 ^ (l & 7))] =
            make_float4(arr[4*q8], arr[4*q8+1], arr[4*q8+2], arr[4*q8+3]);
    __syncthreads();
    const int tb = (base - 5) * CH;              // t = tb + 4f, f = 40..511
    #pragma unroll
    for (int it = 0; it < 8; ++it) {
        const int f = 40 + it * 64 + l;
        const int t = tb + 4 * f;
        if (f < 512 && t < T_LEN) {
            const int k = f >> 3, qq = f & 7;
            const float4 ov = o_st[k * 8 + (qq ^ (k & 7))];
            *reinterpret_cast<float4*>(orow + t) = ov;
        }
    }
}

extern "C" void kernel_launch(void* const* d_in, const int* in_sizes, int n_in,
                              void* d_out, int out_size, void* d_ws, size_t ws_size,
                              hipStream_t stream) {
    const float* u  = (const float*)d_in[0];
    const float* b1 = (const float*)d_in[1];
    const float* a1 = (const float*)d_in[2];
    const float* b2 = (const float*)d_in[3];
    const float* a2 = (const float*)d_in[4];
    float* out = (float*)d_out;

    const int B = in_sizes[0] / T_LEN;   // 512
    dim3 grid(SEGS, B);
    whsys_kernel<<<grid, 64, 0, stream>>>(u, b1, a1, b2, a2, out);
}

// Round 8
// 21.955 us; speedup vs baseline: 1.0852x; 1.0852x over previous
//
#include <hip/hip_runtime.h>

// Wiener-Hammerstein, exact chunk-state, INTRA-KERNEL SOFTWARE PIPELINE.
//   y1 = IIR(b1,a1,n_k=1)(u);  v = whf(y1);  out = IIR(b2,a2,n_k=0)(v)
// R5/R6/R7 all ~21-24us: load/compute/store phases serialize because
// __syncthreads drains vmcnt(0). This version: one row per 256-thr block,
// 4 segments x 4096 samples, double-buffered LDS u; barriers are raw
// {s_waitcnt lgkmcnt(0); s_barrier} so global loads (prefetch seg s+1,
// issued at segment start into regs) and global stores (o_st of seg s-1)
// stay in flight across compute; one vmcnt(0) per segment before the
// staged-u LDS commit (T14 issue-early/write-late).
// Exact state at CH=16: E1 = D1[c-1]+A1*D1[c-2] (A1=C1^16, trunc ~8e-5);
// E2 = D2[c-1]+A2*D2[c-2]+A2^2*D2[c-3]+A2^3*D2[c-4] (trunc ~2e-4);
// v-tails from EXACT y1 tails: tail(c-1) = D1[c-1] + A1*E1[c-1].
// o_st aliases the consumed u buffer (write/read chains separated by B1/B2;
// full audit in session notes). All LDS at the b128 bank floor via XOR swz.

constexpr int T_LEN = 16384;
constexpr int NTH   = 256;
constexpr int NSEG  = 4;
constexpr int QSEG  = 1024;   // float4 quads per segment

#define BAR() asm volatile("s_waitcnt lgkmcnt(0)\ns_barrier" ::: "memory")

__global__ __launch_bounds__(NTH, 2)
void whsys_kernel(const float* __restrict__ u,
                  const float* __restrict__ b1v, const float* __restrict__ a1v,
                  const float* __restrict__ b2v, const float* __restrict__ a2v,
                  float* __restrict__ out)
{
    // buf: u quads at slot g ^ ((g>>4)&3); o_st reuse at slot g ^ ((g>>5)&7).
    __shared__ float4 buf[2][QSEG];          // 32 KB
    __shared__ float4 d1s[256], d2s[256];    // chunk-final states (this seg)
    __shared__ float4 d1h[2][4], d2h[2][4];  // head states (prev-seg tails)
    __shared__ float  uhd[2][4];             // u history (prev-seg last 3)

    const int c = threadIdx.x;
    const float4* __restrict__ urow4 =
        reinterpret_cast<const float4*>(u + (size_t)blockIdx.x * T_LEN);
    float4* __restrict__ orow4 =
        reinterpret_cast<float4*>(out + (size_t)blockIdx.x * T_LEN);

    const float b10=b1v[0], b11=b1v[1], b12=b1v[2];
    const float a10=a1v[0], a11=a1v[1], a12=a1v[2];
    const float b20=b2v[0], b21=b2v[1], b22=b2v[2];
    const float a20=a2v[0], a21=a2v[1], a22=a2v[2];

    // ---- A1 = C1^16, A2 = C2^16 (4 squarings), A2q = A2^2, A2c = A2^3 -----
    float A1[9] = {-a10,-a11,-a12, 1.f,0.f,0.f, 0.f,1.f,0.f};
    float A2[9] = {-a20,-a21,-a22, 1.f,0.f,0.f, 0.f,1.f,0.f};
    float A2q[9], A2c[9];
    #pragma unroll
    for (int it = 0; it < 4; ++it) {
        float B1[9], B2[9];
        #pragma unroll
        for (int i = 0; i < 3; ++i)
            #pragma unroll
            for (int j = 0; j < 3; ++j) {
                B1[i*3+j] = fmaf(A1[i*3], A1[j], fmaf(A1[i*3+1], A1[3+j], A1[i*3+2]*A1[6+j]));
                B2[i*3+j] = fmaf(A2[i*3], A2[j], fmaf(A2[i*3+1], A2[3+j], A2[i*3+2]*A2[6+j]));
            }
        #pragma unroll
        for (int i = 0; i < 9; ++i) { A1[i] = B1[i]; A2[i] = B2[i]; }
    }
    #pragma unroll
    for (int i = 0; i < 3; ++i)
        #pragma unroll
        for (int j = 0; j < 3; ++j)
            A2q[i*3+j] = fmaf(A2[i*3], A2[j], fmaf(A2[i*3+1], A2[3+j], A2[i*3+2]*A2[6+j]));
    #pragma unroll
    for (int i = 0; i < 3; ++i)
        #pragma unroll
        for (int j = 0; j < 3; ++j)
            A2c[i*3+j] = fmaf(A2q[i*3], A2[j], fmaf(A2q[i*3+1], A2[3+j], A2q[i*3+2]*A2[6+j]));

    auto whf = [](float y) -> float {   // -elu(-10/11 y) = med3(ky, 1-e^-ky, 0)
        const float t1 = 0.9090909090909091f * y;
        const float e  = 1.f - __expf(-t1);
        return __builtin_amdgcn_fmed3f(t1, e, 0.f);
    };

    // ---- prologue: stage segment 0 ------------------------------------------
    {
        const int sw = (c >> 4) & 3;
        float4 l3;
        #pragma unroll
        for (int j = 0; j < 4; ++j) {
            const float4 v = urow4[c + 256*j];
            buf[0][(c + 256*j) ^ sw] = v;
            if (j == 3) l3 = v;
        }
        if (c == 255) { uhd[1][1] = l3.y; uhd[1][2] = l3.z; uhd[1][3] = l3.w; }
        if (c < 4) {
            d1h[0][c] = make_float4(0.f,0.f,0.f,0.f);
            d2h[0][c] = make_float4(0.f,0.f,0.f,0.f);
            uhd[0][c] = 0.f;
        }
    }
    __syncthreads();

    float arr[16];

    #pragma unroll
    for (int s = 0; s < NSEG; ++s) {
        const int p = s & 1, pn = p ^ 1;

        // ---- R0: prefetch u(s+1) -> regs (issue-early) -----------------------
        float4 ur0, ur1, ur2, ur3;
        if (s < NSEG-1) {
            const float4* src = urow4 + (s+1)*QSEG;
            ur0 = src[c];  ur1 = src[c+256];  ur2 = src[c+512];  ur3 = src[c+768];
            asm volatile("" :: "v"(ur0.x), "v"(ur1.x), "v"(ur2.x), "v"(ur3.x));
        }
        // ---- R0: store o_st(s-1) from buf[pn] (stores fly across barriers) ---
        if (s > 0) {
            #pragma unroll
            for (int j = 0; j < 4; ++j) {
                const int g = c + 256*j;
                orow4[(s-1)*QSEG + g] = buf[pn][g ^ ((g >> 5) & 7)];
            }
        }
        // ---- pass 1: stage-1 local (zero y-init, exact u) --------------------
        float yr1, yr2, yr3;
        {
            float u1, u2, u3;
            if (c == 0) { u1 = uhd[p][3]; u2 = uhd[p][2]; u3 = uhd[p][1]; }
            else {
                const int g = 4*(c-1) + 3;
                const float4 hq = buf[p][g ^ ((g >> 4) & 3)];
                u1 = hq.w; u2 = hq.z; u3 = hq.y;
            }
            float y1 = 0.f, y2 = 0.f, y3 = 0.f;
            const int rs = (c >> 2) & 3;
            #pragma unroll
            for (int e = 0; e < 4; ++e) {
                const float4 uq = buf[p][4*c + (e ^ rs)];
                const float us[4] = {uq.x, uq.y, uq.z, uq.w};
                #pragma unroll
                for (int r = 0; r < 4; ++r) {
                    const float x = fmaf(b12,u3, fmaf(b11,u2, b10*u1));
                    const float y = fmaf(-a10,y1, fmaf(-a11,y2, fmaf(-a12,y3, x)));
                    arr[4*e+r] = y;
                    u3=u2; u2=u1; u1=us[r];
                    y3=y2; y2=y1; y1=y;
                }
            }
            yr1=y1; yr2=y2; yr3=y3;
            d1s[c] = make_float4(y1, y2, y3, 0.f);
            if (c >= 252) d1h[pn][c-252] = make_float4(y1, y2, y3, 0.f);
        }
        BAR();  // B1: d1s ready (lgkm only; vm ops stay outstanding)

        // ---- pass 2: exact y1 + whf + stage-2 local --------------------------
        {
            const float4 P = (c>=1) ? d1s[c-1] : d1h[p][3];
            const float4 Q = (c>=2) ? d1s[c-2] : d1h[p][2+c];
            const float4 R = (c>=3) ? d1s[c-3] : d1h[p][1+c];
            // E1 = P + A1*Q
            float h1 = fmaf(A1[0],Q.x, fmaf(A1[1],Q.y, fmaf(A1[2],Q.z, P.x)));
            float h2 = fmaf(A1[3],Q.x, fmaf(A1[4],Q.y, fmaf(A1[5],Q.z, P.y)));
            float h3 = fmaf(A1[6],Q.x, fmaf(A1[7],Q.y, fmaf(A1[8],Q.z, P.z)));
            // E1[c-1] = Q + A1*R ; exact tail(c-1) = P + A1*E1[c-1]
            const float emx = fmaf(A1[0],R.x, fmaf(A1[1],R.y, fmaf(A1[2],R.z, Q.x)));
            const float emy = fmaf(A1[3],R.x, fmaf(A1[4],R.y, fmaf(A1[5],R.z, Q.y)));
            const float emz = fmaf(A1[6],R.x, fmaf(A1[7],R.y, fmaf(A1[8],R.z, Q.z)));
            const float tx  = fmaf(A1[0],emx, fmaf(A1[1],emy, fmaf(A1[2],emz, P.x)));
            const float ty  = fmaf(A1[3],emx, fmaf(A1[4],emy, fmaf(A1[5],emz, P.y)));
            float v1r = whf(tx), v2r = whf(ty);
            float z1 = 0.f, z2 = 0.f, z3 = 0.f;
            #pragma unroll
            for (int j = 0; j < 16; ++j) {
                const float hn = fmaf(-a10,h1, fmaf(-a11,h2, -a12*h3));
                h3=h2; h2=h1; h1=hn;
                const float v = whf(arr[j] + hn);
                const float x = fmaf(b22,v2r, fmaf(b21,v1r, b20*v));
                const float z = fmaf(-a20,z1, fmaf(-a21,z2, fmaf(-a22,z3, x)));
                v2r=v1r; v1r=v;
                z3=z2; z2=z1; z1=z;
                arr[j] = z;
            }
            d2s[c] = make_float4(z1, z2, z3, 0.f);
            if (c >= 252) d2h[pn][c-252] = make_float4(z1, z2, z3, 0.f);
        }
        BAR();  // B2: d2s ready

        // ---- pass 3: E2 correction -> exact out ------------------------------
        {
            const float4 Rv = (c>=1) ? d2s[c-1] : d2h[p][3];
            const float4 Sv = (c>=2) ? d2s[c-2] : d2h[p][2+c];
            const float4 Tv = (c>=3) ? d2s[c-3] : d2h[p][1+c];
            const float4 Uv = (c>=4) ? d2s[c-4] : d2h[p][c];
            float g1 = fmaf(A2[0],Sv.x, fmaf(A2[1],Sv.y, fmaf(A2[2],Sv.z,
                       fmaf(A2q[0],Tv.x, fmaf(A2q[1],Tv.y, fmaf(A2q[2],Tv.z,
                       fmaf(A2c[0],Uv.x, fmaf(A2c[1],Uv.y, fmaf(A2c[2],Uv.z, Rv.x)))))))));
            float g2 = fmaf(A2[3],Sv.x, fmaf(A2[4],Sv.y, fmaf(A2[5],Sv.z,
                       fmaf(A2q[3],Tv.x, fmaf(A2q[4],Tv.y, fmaf(A2q[5],Tv.z,
                       fmaf(A2c[3],Uv.x, fmaf(A2c[4],Uv.y, fmaf(A2c[5],Uv.z, Rv.y)))))))));
            float g3 = fmaf(A2[6],Sv.x, fmaf(A2[7],Sv.y, fmaf(A2[8],Sv.z,
                       fmaf(A2q[6],Tv.x, fmaf(A2q[7],Tv.y, fmaf(A2q[8],Tv.z,
                       fmaf(A2c[6],Uv.x, fmaf(A2c[7],Uv.y, fmaf(A2c[8],Uv.z, Rv.z)))))))));
            #pragma unroll
            for (int j = 0; j < 16; ++j) {
                const float gn = fmaf(-a20,g1, fmaf(-a21,g2, -a22*g3));
                g3=g2; g2=g1; g1=gn;
                arr[j] += gn;
            }
        }
        // ---- o_st(s): write exact outputs into buf[p] (aliases consumed u) ---
        {
            const int ow = (c >> 3) & 7;
            #pragma unroll
            for (int e = 0; e < 4; ++e)
                buf[p][(4*c + e) ^ ow] =
                    make_float4(arr[4*e], arr[4*e+1], arr[4*e+2], arr[4*e+3]);
        }
        // ---- staged-u commit (write-late): regs -> buf[pn] -------------------
        if (s < NSEG-1) {
            asm volatile("s_waitcnt vmcnt(0)" ::: "memory");
            const int sw = (c >> 4) & 3;
            buf[pn][(c +   0) ^ sw] = ur0;
            buf[pn][(c + 256) ^ sw] = ur1;
            buf[pn][(c + 512) ^ sw] = ur2;
            buf[pn][(c + 768) ^ sw] = ur3;
            if (c == 255) { uhd[p][1] = ur3.y; uhd[p][2] = ur3.z; uhd[p][3] = ur3.w; }
        }
        BAR();  // B3: next u-buffer + o_st ready
    }

    // ---- epilogue: store o_st(3) from buf[1] --------------------------------
    #pragma unroll
    for (int j = 0; j < 4; ++j) {
        const int g = c + 256*j;
        orow4[(NSEG-1)*QSEG + g] = buf[1][g ^ ((g >> 5) & 7)];
    }
}

extern "C" void kernel_launch(void* const* d_in, const int* in_sizes, int n_in,
                              void* d_out, int out_size, void* d_ws, size_t ws_size,
                              hipStream_t stream) {
    const float* u  = (const float*)d_in[0];
    const float* b1 = (const float*)d_in[1];
    const float* a1 = (const float*)d_in[2];
    const float* b2 = (const float*)d_in[3];
    const float* a2 = (const float*)d_in[4];
    float* out = (float*)d_out;

    const int B = in_sizes[0] / T_LEN;   // 512
    whsys_kernel<<<B, NTH, 0, stream>>>(u, b1, a1, b2, a2, out);
}